// Round 1
// baseline (1267.620 us; speedup 1.0000x reference)
//
#include <hip/hip_runtime.h>
#include <hip/hip_bf16.h>

// Problem constants
#define D_ 512
#define M_ 128
#define H_ 32
#define NT_ 160            // M_+H_: concatenated output cols
#define P_ 32              // points per block
#define NPTS_ 65536        // N
#define NPAD_ 520          // nx LDS row stride in bf16 (512+8, keeps 16B align)
#define WPAD_ 72           // W slice LDS row stride in bf16 (64+8)
#define OPAD_ 165          // out LDS row stride in floats (conflict-free transpose)
#define KS_ 64             // staged K slice
#define NKS_ 8             // 512/64

typedef __attribute__((ext_vector_type(8))) short bf16x8;
typedef __attribute__((ext_vector_type(4))) short short4v;
typedef __attribute__((ext_vector_type(4))) float f32x4;

__device__ __forceinline__ short bf16bits(float f) {
    __hip_bfloat16 h = __float2bfloat16(f);
    return *reinterpret_cast<short*>(&h);
}

// Convert W_lin (128x512) and W_t1 (32x512) fp32 -> bf16 concat [160][512]; zero sums.
__global__ __launch_bounds__(256) void prep_kernel(
    const float* __restrict__ W_lin, const float* __restrict__ W_t1,
    __hip_bfloat16* __restrict__ wcat, float* __restrict__ sums)
{
    int idx = blockIdx.x * 256 + threadIdx.x;
    if (idx < M_ * D_)       wcat[idx] = __float2bfloat16(W_lin[idx]);
    else if (idx < NT_ * D_) wcat[idx] = __float2bfloat16(W_t1[idx - M_ * D_]);
    if (idx < 256) sums[idx] = 0.0f;
}

__global__ __launch_bounds__(256) void main_kernel(
    const float* __restrict__ x, const float* __restrict__ mass,
    const float* __restrict__ ln_g, const float* __restrict__ ln_b,
    const float* __restrict__ b_lin, const float* __restrict__ W_t2,
    const float* __restrict__ b_t2, const __hip_bfloat16* __restrict__ wcat,
    float* __restrict__ out_tf, float* __restrict__ out_tit,
    float* __restrict__ sums)
{
    __shared__ __align__(16) short nx_s[P_ * NPAD_];     // 33,280 B
    __shared__ __align__(16) float ubuf[5760];           // 23,040 B union: W slice (bf16) / out tile (f32)
    __shared__ float tau_s[P_];

    short* wslice = reinterpret_cast<short*>(ubuf);
    float* out_l  = ubuf;

    const int tid  = threadIdx.x;
    const int lane = tid & 63;
    const int wave = tid >> 6;
    const int g0   = blockIdx.x * P_;       // first global point of block
    const int b_idx = g0 >> 16;             // g0 / N
    const int n0    = g0 & (NPTS_ - 1);

    // ---------------- Phase 1: LayerNorm -> bf16 nx in LDS ----------------
    const int k0 = 4 * lane;
    const int k1 = 256 + 4 * lane;
    const float4 gv0 = *reinterpret_cast<const float4*>(ln_g + k0);
    const float4 gv1 = *reinterpret_cast<const float4*>(ln_g + k1);
    const float4 bv0 = *reinterpret_cast<const float4*>(ln_b + k0);
    const float4 bv1 = *reinterpret_cast<const float4*>(ln_b + k1);

    for (int p = wave; p < P_; p += 4) {
        const float* row = x + (size_t)(g0 + p) * D_;
        const float4 v0 = *reinterpret_cast<const float4*>(row + k0);
        const float4 v1 = *reinterpret_cast<const float4*>(row + k1);
        float s = v0.x + v0.y + v0.z + v0.w + v1.x + v1.y + v1.z + v1.w;
        float q = v0.x*v0.x + v0.y*v0.y + v0.z*v0.z + v0.w*v0.w
                + v1.x*v1.x + v1.y*v1.y + v1.z*v1.z + v1.w*v1.w;
        #pragma unroll
        for (int off = 32; off >= 1; off >>= 1) {
            s += __shfl_xor(s, off);
            q += __shfl_xor(q, off);
        }
        const float mean = s * (1.0f / 512.0f);
        const float var  = q * (1.0f / 512.0f) - mean * mean;
        const float rstd = rsqrtf(var + 1e-5f);

        short4v pk0, pk1;
        pk0.x = bf16bits((v0.x - mean) * rstd * gv0.x + bv0.x);
        pk0.y = bf16bits((v0.y - mean) * rstd * gv0.y + bv0.y);
        pk0.z = bf16bits((v0.z - mean) * rstd * gv0.z + bv0.z);
        pk0.w = bf16bits((v0.w - mean) * rstd * gv0.w + bv0.w);
        pk1.x = bf16bits((v1.x - mean) * rstd * gv1.x + bv1.x);
        pk1.y = bf16bits((v1.y - mean) * rstd * gv1.y + bv1.y);
        pk1.z = bf16bits((v1.z - mean) * rstd * gv1.z + bv1.z);
        pk1.w = bf16bits((v1.w - mean) * rstd * gv1.w + bv1.w);
        *reinterpret_cast<short4v*>(&nx_s[p * NPAD_ + k0]) = pk0;
        *reinterpret_cast<short4v*>(&nx_s[p * NPAD_ + k1]) = pk1;
    }

    // ---------------- Phase 2: MFMA GEMM nx(32x512) @ Wcat^T(512x160) ----------------
    const int pt   = wave >> 1;           // point tile: 0 or 1 (rows 0-15 / 16-31)
    const int ncol = (wave & 1) * 80;     // col range: 0-79 or 80-159
    const int rrow = lane & 15;
    const int quad = lane >> 4;

    f32x4 acc[5];
    #pragma unroll
    for (int i = 0; i < 5; ++i) acc[i] = (f32x4){0.f, 0.f, 0.f, 0.f};

    for (int ks = 0; ks < NKS_; ++ks) {
        __syncthreads();   // wslice free to overwrite (also covers phase-1 completion on ks==0)
        // stage W rows [0,160) x k [ks*64, ks*64+64) : 1280 chunks of 16B
        for (int c = tid; c < NT_ * 8; c += 256) {
            const int r  = c >> 3;
            const int ko = (c & 7) * 8;
            bf16x8 v = *reinterpret_cast<const bf16x8*>(
                reinterpret_cast<const short*>(wcat) + r * D_ + ks * KS_ + ko);
            *reinterpret_cast<bf16x8*>(&wslice[r * WPAD_ + ko]) = v;
        }
        __syncthreads();
        #pragma unroll
        for (int kk = 0; kk < 2; ++kk) {
            const int ko = kk * 32 + quad * 8;
            const bf16x8 a = *reinterpret_cast<const bf16x8*>(
                &nx_s[(pt * 16 + rrow) * NPAD_ + ks * KS_ + ko]);
            #pragma unroll
            for (int i = 0; i < 5; ++i) {
                const bf16x8 b = *reinterpret_cast<const bf16x8*>(
                    &wslice[(ncol + i * 16 + rrow) * WPAD_ + ko]);
                acc[i] = __builtin_amdgcn_mfma_f32_16x16x32_bf16(a, b, acc[i], 0, 0, 0);
            }
        }
    }
    __syncthreads();
    // spill accumulators to LDS out tile: row = point, col = output index
    #pragma unroll
    for (int i = 0; i < 5; ++i) {
        #pragma unroll
        for (int r = 0; r < 4; ++r) {
            out_l[(pt * 16 + quad * 4 + r) * OPAD_ + ncol + i * 16 + rrow] = acc[i][r];
        }
    }
    __syncthreads();

    // ---------------- Phase 3a: temperature head (GELU exact -> softplus -> clamp) ----------------
    {
        const int p  = tid >> 3;
        const int j4 = (tid & 7) * 4;
        float s = 0.0f;
        #pragma unroll
        for (int jj = 0; jj < 4; ++jj) {
            const float hv = out_l[p * OPAD_ + M_ + j4 + jj];
            const float ge = 0.5f * hv * (1.0f + erff(hv * 0.70710678118f));
            s += ge * W_t2[j4 + jj];
        }
        s += __shfl_xor(s, 1);
        s += __shfl_xor(s, 2);
        s += __shfl_xor(s, 4);
        if ((tid & 7) == 0) {
            const float xx = s + b_t2[0];
            const float sp = fmaxf(xx, 0.0f) + log1pf(expf(-fabsf(xx)));
            tau_s[p] = fminf(fmaxf(sp, 0.01f), 3.0f);
        }
    }
    __syncthreads();

    // ---------------- Phase 3b: softmax per point; write trial_func; stash tf*mass ----------------
    for (int p = wave * 8; p < wave * 8 + 8; ++p) {
        const int g = g0 + p;
        const float itau = 1.0f / tau_s[p];
        const float mv   = mass[g];
        const int c0 = lane, c1 = lane + 64;
        float z0 = (out_l[p * OPAD_ + c0] + b_lin[c0]) * itau;
        float z1 = (out_l[p * OPAD_ + c1] + b_lin[c1]) * itau;
        float mx = fmaxf(z0, z1);
        #pragma unroll
        for (int off = 32; off >= 1; off >>= 1) mx = fmaxf(mx, __shfl_xor(mx, off));
        const float e0 = __expf(z0 - mx);
        const float e1 = __expf(z1 - mx);
        float ss = e0 + e1;
        #pragma unroll
        for (int off = 32; off >= 1; off >>= 1) ss += __shfl_xor(ss, off);
        const float inv = 1.0f / ss;
        const float t0 = e0 * inv, t1 = e1 * inv;
        out_tf[(size_t)g * M_ + c0] = t0;
        out_tf[(size_t)g * M_ + c1] = t1;
        out_l[p * OPAD_ + c0] = t0 * mv;
        out_l[p * OPAD_ + c1] = t1 * mv;
    }
    __syncthreads();

    // ---------------- Phase 3c: transposed write of trial_in_t + per-mode block sums ----------------
    {
        const int p  = tid & 31;
        const int mr = tid >> 5;     // 0..7
        #pragma unroll
        for (int i = 0; i < 16; ++i) {
            const int m = i * 8 + mr;
            const float v = out_l[p * OPAD_ + m];
            out_tit[(size_t)b_idx * M_ * NPTS_ + (size_t)m * NPTS_ + n0 + p] = v;
            float r = v;
            r += __shfl_xor(r, 1);
            r += __shfl_xor(r, 2);
            r += __shfl_xor(r, 4);
            r += __shfl_xor(r, 8);
            r += __shfl_xor(r, 16);
            if ((lane & 31) == 0) atomicAdd(&sums[b_idx * M_ + m], r);
        }
    }
}

__global__ void finish_kernel(const float* __restrict__ sums, float* __restrict__ out_inv) {
    const int t = threadIdx.x;
    out_inv[t] = 1.0f / (sums[t] + 1e-6f);
}

extern "C" void kernel_launch(void* const* d_in, const int* in_sizes, int n_in,
                              void* d_out, int out_size, void* d_ws, size_t ws_size,
                              hipStream_t stream) {
    const float* x     = (const float*)d_in[0];
    const float* mass  = (const float*)d_in[1];
    const float* ln_g  = (const float*)d_in[2];
    const float* ln_b  = (const float*)d_in[3];
    const float* W_lin = (const float*)d_in[4];
    const float* b_lin = (const float*)d_in[5];
    const float* W_t1  = (const float*)d_in[6];
    const float* W_t2  = (const float*)d_in[7];
    const float* b_t2  = (const float*)d_in[8];

    __hip_bfloat16* wcat = (__hip_bfloat16*)d_ws;                       // 160*512*2 = 163,840 B
    float* sums          = (float*)((char*)d_ws + NT_ * D_ * 2);        // 256 floats

    float* out_tf  = (float*)d_out;                                     // (B,N,M)
    float* out_tit = out_tf + (size_t)2 * NPTS_ * M_;                   // (B,M,N)
    float* out_inv = out_tit + (size_t)2 * NPTS_ * M_;                  // (B,M,1)

    prep_kernel<<<(NT_ * D_ + 255) / 256, 256, 0, stream>>>(W_lin, W_t1, wcat, sums);

    const int nblocks = (2 * NPTS_) / P_;   // 4096
    main_kernel<<<nblocks, 256, 0, stream>>>(x, mass, ln_g, ln_b, b_lin, W_t2, b_t2,
                                             wcat, out_tf, out_tit, sums);

    finish_kernel<<<1, 256, 0, stream>>>(sums, out_inv);
}

// Round 2
// 528.615 us; speedup vs baseline: 2.3980x; 2.3980x over previous
//
#include <hip/hip_runtime.h>
#include <hip/hip_bf16.h>

// Problem constants
#define D_ 512
#define M_ 128
#define H_ 32
#define NT_ 160            // M_+H_: concatenated output cols
#define P_ 32              // points per block
#define NPTS_ 65536        // N
#define NPAD_ 520          // nx LDS row stride in bf16 (512+8: 16B-aligned rows, 2-way bank alias = free)
#define OPAD_ 165          // out LDS row stride in floats (stride%32=5 -> conflict-free transpose)
#define BLKS_PER_B 2048    // N / P_

typedef __attribute__((ext_vector_type(8))) short bf16x8;
typedef __attribute__((ext_vector_type(4))) short short4v;
typedef __attribute__((ext_vector_type(4))) float f32x4;

__device__ __forceinline__ short bf16bits(float f) {
    __hip_bfloat16 h = __float2bfloat16(f);
    return *reinterpret_cast<short*>(&h);
}

// Convert W_lin (128x512) and W_t1 (32x512) fp32 -> bf16 concat [160][512].
__global__ __launch_bounds__(256) void prep_kernel(
    const float* __restrict__ W_lin, const float* __restrict__ W_t1,
    __hip_bfloat16* __restrict__ wcat)
{
    int idx = blockIdx.x * 256 + threadIdx.x;
    if (idx < M_ * D_)       wcat[idx] = __float2bfloat16(W_lin[idx]);
    else if (idx < NT_ * D_) wcat[idx] = __float2bfloat16(W_t1[idx - M_ * D_]);
}

__global__ __launch_bounds__(256, 4) void main_kernel(
    const float* __restrict__ x, const float* __restrict__ mass,
    const float* __restrict__ ln_g, const float* __restrict__ ln_b,
    const float* __restrict__ b_lin, const float* __restrict__ W_t2,
    const float* __restrict__ b_t2, const __hip_bfloat16* __restrict__ wcat,
    float* __restrict__ out_tf, float* __restrict__ out_tit,
    float* __restrict__ part)
{
    // nx (bf16, 33,280 B) unions with the f32 epilogue tile (21,120 B)
    __shared__ __align__(16) short nx_s[P_ * NPAD_];
    __shared__ float tau_s[P_];
    float* out_l = reinterpret_cast<float*>(nx_s);

    const int tid  = threadIdx.x;
    const int lane = tid & 63;
    const int wave = tid >> 6;
    const int g0   = blockIdx.x * P_;        // first global point of block
    const int b_idx = g0 >> 16;              // batch index
    const int n0    = g0 & (NPTS_ - 1);

    // ---------------- Phase 1: LayerNorm -> bf16 nx in LDS ----------------
    const int k0 = 4 * lane;
    const int k1 = 256 + 4 * lane;
    const float4 gv0 = *reinterpret_cast<const float4*>(ln_g + k0);
    const float4 gv1 = *reinterpret_cast<const float4*>(ln_g + k1);
    const float4 bv0 = *reinterpret_cast<const float4*>(ln_b + k0);
    const float4 bv1 = *reinterpret_cast<const float4*>(ln_b + k1);

    for (int p = wave; p < P_; p += 4) {
        const float* row = x + (size_t)(g0 + p) * D_;
        const float4 v0 = *reinterpret_cast<const float4*>(row + k0);
        const float4 v1 = *reinterpret_cast<const float4*>(row + k1);
        float s = v0.x + v0.y + v0.z + v0.w + v1.x + v1.y + v1.z + v1.w;
        float q = v0.x*v0.x + v0.y*v0.y + v0.z*v0.z + v0.w*v0.w
                + v1.x*v1.x + v1.y*v1.y + v1.z*v1.z + v1.w*v1.w;
        #pragma unroll
        for (int off = 32; off >= 1; off >>= 1) {
            s += __shfl_xor(s, off);
            q += __shfl_xor(q, off);
        }
        const float mean = s * (1.0f / 512.0f);
        const float var  = q * (1.0f / 512.0f) - mean * mean;
        const float rstd = rsqrtf(var + 1e-5f);

        short4v pk0, pk1;
        pk0.x = bf16bits((v0.x - mean) * rstd * gv0.x + bv0.x);
        pk0.y = bf16bits((v0.y - mean) * rstd * gv0.y + bv0.y);
        pk0.z = bf16bits((v0.z - mean) * rstd * gv0.z + bv0.z);
        pk0.w = bf16bits((v0.w - mean) * rstd * gv0.w + bv0.w);
        pk1.x = bf16bits((v1.x - mean) * rstd * gv1.x + bv1.x);
        pk1.y = bf16bits((v1.y - mean) * rstd * gv1.y + bv1.y);
        pk1.z = bf16bits((v1.z - mean) * rstd * gv1.z + bv1.z);
        pk1.w = bf16bits((v1.w - mean) * rstd * gv1.w + bv1.w);
        *reinterpret_cast<short4v*>(&nx_s[p * NPAD_ + k0]) = pk0;
        *reinterpret_cast<short4v*>(&nx_s[p * NPAD_ + k1]) = pk1;
    }
    __syncthreads();   // barrier 1: nx ready

    // ---------------- Phase 2: barrier-free MFMA GEMM; B-frags straight from L2 ----------------
    const int pt   = wave >> 1;           // point tile: rows 0-15 / 16-31
    const int ncol = (wave & 1) * 80;     // col range: 0-79 or 80-159
    const int rrow = lane & 15;
    const int quad = lane >> 4;

    f32x4 acc[5];
    #pragma unroll
    for (int i = 0; i < 5; ++i) acc[i] = (f32x4){0.f, 0.f, 0.f, 0.f};

    const short* wg = reinterpret_cast<const short*>(wcat) + (ncol + rrow) * D_;
    const short* ag = &nx_s[(pt * 16 + rrow) * NPAD_];

    #pragma unroll 2
    for (int kt = 0; kt < 16; ++kt) {      // 16 chunks of K=32
        const int ko = kt * 32 + quad * 8;
        const bf16x8 a = *reinterpret_cast<const bf16x8*>(ag + ko);
        #pragma unroll
        for (int i = 0; i < 5; ++i) {
            const bf16x8 b = *reinterpret_cast<const bf16x8*>(wg + i * 16 * D_ + ko);
            acc[i] = __builtin_amdgcn_mfma_f32_16x16x32_bf16(a, b, acc[i], 0, 0, 0);
        }
    }
    __syncthreads();   // barrier 2: all nx reads done; out_l may overwrite

    // spill accumulators: row = point, col = output index
    #pragma unroll
    for (int i = 0; i < 5; ++i) {
        #pragma unroll
        for (int r = 0; r < 4; ++r) {
            out_l[(pt * 16 + quad * 4 + r) * OPAD_ + ncol + i * 16 + rrow] = acc[i][r];
        }
    }
    __syncthreads();   // barrier 3: tile complete

    // ---------------- Phase 3a: temperature head (GELU exact -> softplus -> clamp) ----------------
    {
        const int p  = tid >> 3;
        const int j4 = (tid & 7) * 4;
        float s = 0.0f;
        #pragma unroll
        for (int jj = 0; jj < 4; ++jj) {
            const float hv = out_l[p * OPAD_ + M_ + j4 + jj];
            const float ge = 0.5f * hv * (1.0f + erff(hv * 0.70710678118f));
            s += ge * W_t2[j4 + jj];
        }
        s += __shfl_xor(s, 1);
        s += __shfl_xor(s, 2);
        s += __shfl_xor(s, 4);
        if ((tid & 7) == 0) {
            const float xx = s + b_t2[0];
            const float sp = fmaxf(xx, 0.0f) + log1pf(expf(-fabsf(xx)));
            tau_s[p] = fminf(fmaxf(sp, 0.01f), 3.0f);
        }
    }
    // no barrier: 3b's tau_s/out_l deps are wave-internal (same rows, disjoint cols)

    // ---------------- Phase 3b: softmax per point; write trial_func; stash tf*mass ----------------
    const float bl0 = b_lin[lane];
    const float bl1 = b_lin[lane + 64];
    for (int p = wave * 8; p < wave * 8 + 8; ++p) {
        const int g = g0 + p;
        const float itau = 1.0f / tau_s[p];
        const float mv   = mass[g];
        float z0 = (out_l[p * OPAD_ + lane] + bl0) * itau;
        float z1 = (out_l[p * OPAD_ + lane + 64] + bl1) * itau;
        float mx = fmaxf(z0, z1);
        #pragma unroll
        for (int off = 32; off >= 1; off >>= 1) mx = fmaxf(mx, __shfl_xor(mx, off));
        const float e0 = __expf(z0 - mx);
        const float e1 = __expf(z1 - mx);
        float ss = e0 + e1;
        #pragma unroll
        for (int off = 32; off >= 1; off >>= 1) ss += __shfl_xor(ss, off);
        const float inv = 1.0f / ss;
        const float t0 = e0 * inv, t1 = e1 * inv;
        out_tf[(size_t)g * M_ + lane]      = t0;
        out_tf[(size_t)g * M_ + lane + 64] = t1;
        out_l[p * OPAD_ + lane]      = t0 * mv;
        out_l[p * OPAD_ + lane + 64] = t1 * mv;
    }
    __syncthreads();   // barrier 4: tf*mass tile complete

    // ---------------- Phase 3c: transposed write of trial_in_t ----------------
    {
        const int p  = tid & 31;
        const int mr = tid >> 5;     // 0..7
        #pragma unroll
        for (int i = 0; i < 16; ++i) {
            const int m = i * 8 + mr;
            out_tit[(size_t)b_idx * M_ * NPTS_ + (size_t)m * NPTS_ + n0 + p] =
                out_l[p * OPAD_ + m];
        }
    }

    // ---------------- Phase 3d: per-block column sums -> workspace partials ----------------
    if (tid < M_) {
        float s = 0.0f;
        #pragma unroll
        for (int p = 0; p < P_; ++p) s += out_l[p * OPAD_ + tid];
        part[((size_t)(b_idx * M_ + tid)) * BLKS_PER_B + (blockIdx.x & (BLKS_PER_B - 1))] = s;
    }
}

// Reduce partials: one block per (b,m); 2048 partials each.
__global__ __launch_bounds__(256) void finish_kernel(
    const float* __restrict__ part, float* __restrict__ out_inv)
{
    __shared__ float wsum[4];
    const int j = blockIdx.x;           // b*128 + m
    const int t = threadIdx.x;
    const float* row = part + (size_t)j * BLKS_PER_B;
    float s = 0.0f;
    #pragma unroll
    for (int i = 0; i < 8; ++i) s += row[i * 256 + t];
    #pragma unroll
    for (int off = 32; off >= 1; off >>= 1) s += __shfl_xor(s, off);
    if ((t & 63) == 0) wsum[t >> 6] = s;
    __syncthreads();
    if (t == 0) out_inv[j] = 1.0f / (wsum[0] + wsum[1] + wsum[2] + wsum[3] + 1e-6f);
}

extern "C" void kernel_launch(void* const* d_in, const int* in_sizes, int n_in,
                              void* d_out, int out_size, void* d_ws, size_t ws_size,
                              hipStream_t stream) {
    const float* x     = (const float*)d_in[0];
    const float* mass  = (const float*)d_in[1];
    const float* ln_g  = (const float*)d_in[2];
    const float* ln_b  = (const float*)d_in[3];
    const float* W_lin = (const float*)d_in[4];
    const float* b_lin = (const float*)d_in[5];
    const float* W_t1  = (const float*)d_in[6];
    const float* W_t2  = (const float*)d_in[7];
    const float* b_t2  = (const float*)d_in[8];

    __hip_bfloat16* wcat = (__hip_bfloat16*)d_ws;                    // 163,840 B
    float* part          = (float*)((char*)d_ws + NT_ * D_ * 2);     // 2*128*2048 floats = 2 MB

    float* out_tf  = (float*)d_out;                                  // (B,N,M)
    float* out_tit = out_tf + (size_t)2 * NPTS_ * M_;                // (B,M,N)
    float* out_inv = out_tit + (size_t)2 * NPTS_ * M_;               // (B,M,1)

    prep_kernel<<<(NT_ * D_ + 255) / 256, 256, 0, stream>>>(W_lin, W_t1, wcat);

    const int nblocks = (2 * NPTS_) / P_;   // 4096
    main_kernel<<<nblocks, 256, 0, stream>>>(x, mass, ln_g, ln_b, b_lin, W_t2, b_t2,
                                             wcat, out_tf, out_tit, part);

    finish_kernel<<<2 * M_, 256, 0, stream>>>(part, out_inv);
}

// Round 3
// 519.509 us; speedup vs baseline: 2.4400x; 1.0175x over previous
//
#include <hip/hip_runtime.h>
#include <hip/hip_bf16.h>

// Problem constants
#define D_ 512
#define M_ 128
#define H_ 32
#define NT_ 160            // M_+H_: concatenated output cols
#define P_ 32              // points per block
#define NPTS_ 65536        // N
#define NPAD_ 520          // nx LDS row stride in bf16 (512+8: 16B-aligned rows, 2-way bank alias = free)
#define OPAD_ 165          // out LDS row stride in floats (stride%32=5 -> conflict-free transpose)
#define BLKS_PER_B 2048    // N / P_

typedef __attribute__((ext_vector_type(8))) short bf16x8;
typedef __attribute__((ext_vector_type(4))) short short4v;
typedef __attribute__((ext_vector_type(4))) float f32x4;

__device__ __forceinline__ short bf16bits(float f) {
    __hip_bfloat16 h = __float2bfloat16(f);
    return *reinterpret_cast<short*>(&h);
}

// Convert W_lin (128x512) and W_t1 (32x512) fp32 -> bf16 concat [160][512].
__global__ __launch_bounds__(256) void prep_kernel(
    const float* __restrict__ W_lin, const float* __restrict__ W_t1,
    __hip_bfloat16* __restrict__ wcat)
{
    int idx = blockIdx.x * 256 + threadIdx.x;
    if (idx < M_ * D_)       wcat[idx] = __float2bfloat16(W_lin[idx]);
    else if (idx < NT_ * D_) wcat[idx] = __float2bfloat16(W_t1[idx - M_ * D_]);
}

__global__ __launch_bounds__(256, 4) void main_kernel(
    const float* __restrict__ x, const float* __restrict__ mass,
    const float* __restrict__ ln_g, const float* __restrict__ ln_b,
    const float* __restrict__ b_lin, const float* __restrict__ W_t2,
    const float* __restrict__ b_t2, const __hip_bfloat16* __restrict__ wcat,
    float* __restrict__ out_tf, float* __restrict__ out_tit,
    float* __restrict__ part)
{
    // nx (bf16, 33,280 B) unions with the f32 epilogue tile (21,120 B)
    __shared__ __align__(16) short nx_s[P_ * NPAD_];
    __shared__ float tau_s[P_];
    float* out_l = reinterpret_cast<float*>(nx_s);

    const int tid  = threadIdx.x;
    const int lane = tid & 63;
    const int wave = tid >> 6;
    const int g0   = blockIdx.x * P_;        // first global point of block
    const int b_idx = g0 >> 16;              // batch index
    const int n0    = g0 & (NPTS_ - 1);

    // ---------------- Phase 1: LayerNorm -> bf16 nx in LDS ----------------
    // All 16 x-loads issued up front (fully unrolled) so HBM latency is paid once.
    const int k0 = 4 * lane;
    const int k1 = 256 + 4 * lane;

    float4 v0[8], v1[8];
    const float* rowbase = x + (size_t)(g0 + wave) * D_;
    #pragma unroll
    for (int i = 0; i < 8; ++i) {
        const float* row = rowbase + (size_t)(4 * i) * D_;
        v0[i] = *reinterpret_cast<const float4*>(row + k0);
        v1[i] = *reinterpret_cast<const float4*>(row + k1);
    }

    const float4 gv0 = *reinterpret_cast<const float4*>(ln_g + k0);
    const float4 gv1 = *reinterpret_cast<const float4*>(ln_g + k1);
    const float4 bv0 = *reinterpret_cast<const float4*>(ln_b + k0);
    const float4 bv1 = *reinterpret_cast<const float4*>(ln_b + k1);

    #pragma unroll
    for (int i = 0; i < 8; ++i) {
        const int p = wave + 4 * i;
        float s = v0[i].x + v0[i].y + v0[i].z + v0[i].w
                + v1[i].x + v1[i].y + v1[i].z + v1[i].w;
        float q = v0[i].x*v0[i].x + v0[i].y*v0[i].y + v0[i].z*v0[i].z + v0[i].w*v0[i].w
                + v1[i].x*v1[i].x + v1[i].y*v1[i].y + v1[i].z*v1[i].z + v1[i].w*v1[i].w;
        #pragma unroll
        for (int off = 32; off >= 1; off >>= 1) {
            s += __shfl_xor(s, off);
            q += __shfl_xor(q, off);
        }
        const float mean = s * (1.0f / 512.0f);
        const float var  = q * (1.0f / 512.0f) - mean * mean;
        const float rstd = rsqrtf(var + 1e-5f);

        short4v pk0, pk1;
        pk0.x = bf16bits((v0[i].x - mean) * rstd * gv0.x + bv0.x);
        pk0.y = bf16bits((v0[i].y - mean) * rstd * gv0.y + bv0.y);
        pk0.z = bf16bits((v0[i].z - mean) * rstd * gv0.z + bv0.z);
        pk0.w = bf16bits((v0[i].w - mean) * rstd * gv0.w + bv0.w);
        pk1.x = bf16bits((v1[i].x - mean) * rstd * gv1.x + bv1.x);
        pk1.y = bf16bits((v1[i].y - mean) * rstd * gv1.y + bv1.y);
        pk1.z = bf16bits((v1[i].z - mean) * rstd * gv1.z + bv1.z);
        pk1.w = bf16bits((v1[i].w - mean) * rstd * gv1.w + bv1.w);
        *reinterpret_cast<short4v*>(&nx_s[p * NPAD_ + k0]) = pk0;
        *reinterpret_cast<short4v*>(&nx_s[p * NPAD_ + k1]) = pk1;
    }
    __syncthreads();   // barrier 1: nx ready

    // ---------------- Phase 2: MFMA GEMM, software-pipelined B frags from L2 ----------------
    const int pt   = wave >> 1;           // point tile: rows 0-15 / 16-31
    const int ncol = (wave & 1) * 80;     // col range: 0-79 or 80-159
    const int rrow = lane & 15;
    const int quad = lane >> 4;

    f32x4 acc[5];
    #pragma unroll
    for (int i = 0; i < 5; ++i) acc[i] = (f32x4){0.f, 0.f, 0.f, 0.f};

    const short* wg = reinterpret_cast<const short*>(wcat) + (ncol + rrow) * D_ + quad * 8;
    const short* ag = &nx_s[(pt * 16 + rrow) * NPAD_ + quad * 8];

#define BLOAD(i, kt) (*reinterpret_cast<const bf16x8*>(wg + (i) * 16 * D_ + (kt) * 32))

    bf16x8 b0[5], b1[5];
    #pragma unroll
    for (int i = 0; i < 5; ++i) b0[i] = BLOAD(i, 0);

    #pragma unroll
    for (int kp = 0; kp < 8; ++kp) {
        #pragma unroll
        for (int i = 0; i < 5; ++i) b1[i] = BLOAD(i, 2 * kp + 1);
        const bf16x8 a0 = *reinterpret_cast<const bf16x8*>(ag + (2 * kp) * 32);
        #pragma unroll
        for (int i = 0; i < 5; ++i)
            acc[i] = __builtin_amdgcn_mfma_f32_16x16x32_bf16(a0, b0[i], acc[i], 0, 0, 0);
        if (kp < 7) {
            #pragma unroll
            for (int i = 0; i < 5; ++i) b0[i] = BLOAD(i, 2 * kp + 2);
        }
        const bf16x8 a1 = *reinterpret_cast<const bf16x8*>(ag + (2 * kp + 1) * 32);
        #pragma unroll
        for (int i = 0; i < 5; ++i)
            acc[i] = __builtin_amdgcn_mfma_f32_16x16x32_bf16(a1, b1[i], acc[i], 0, 0, 0);
    }
#undef BLOAD
    __syncthreads();   // barrier 2: all nx reads done; out_l may overwrite

    // spill accumulators: row = point, col = output index
    #pragma unroll
    for (int i = 0; i < 5; ++i) {
        #pragma unroll
        for (int r = 0; r < 4; ++r) {
            out_l[(pt * 16 + quad * 4 + r) * OPAD_ + ncol + i * 16 + rrow] = acc[i][r];
        }
    }
    __syncthreads();   // barrier 3: tile complete

    // ---------------- Phase 3a: temperature head (GELU exact -> softplus -> clamp) ----------------
    {
        const int p  = tid >> 3;
        const int j4 = (tid & 7) * 4;
        float s = 0.0f;
        #pragma unroll
        for (int jj = 0; jj < 4; ++jj) {
            const float hv = out_l[p * OPAD_ + M_ + j4 + jj];
            const float ge = 0.5f * hv * (1.0f + erff(hv * 0.70710678118f));
            s += ge * W_t2[j4 + jj];
        }
        s += __shfl_xor(s, 1);
        s += __shfl_xor(s, 2);
        s += __shfl_xor(s, 4);
        if ((tid & 7) == 0) {
            const float xx = s + b_t2[0];
            const float sp = fmaxf(xx, 0.0f) + log1pf(expf(-fabsf(xx)));
            tau_s[p] = fminf(fmaxf(sp, 0.01f), 3.0f);
        }
    }
    // no barrier: 3b's tau_s/out_l deps are wave-internal

    // ---------------- Phase 3b: softmax, 32 lanes per point (2 points/wave in flight) ----------------
    {
        const int half = lane >> 5;       // which point of the pair
        const int c    = lane & 31;       // mode subset: c, c+32, c+64, c+96
        float bl[4];
        #pragma unroll
        for (int j = 0; j < 4; ++j) bl[j] = b_lin[c + 32 * j];

        #pragma unroll
        for (int it = 0; it < 4; ++it) {
            const int p = wave * 8 + it * 2 + half;
            const int g = g0 + p;
            const float itau = 1.0f / tau_s[p];
            const float mv   = mass[g];
            float z[4];
            #pragma unroll
            for (int j = 0; j < 4; ++j)
                z[j] = (out_l[p * OPAD_ + c + 32 * j] + bl[j]) * itau;
            float mx = fmaxf(fmaxf(z[0], z[1]), fmaxf(z[2], z[3]));
            #pragma unroll
            for (int off = 16; off >= 1; off >>= 1) mx = fmaxf(mx, __shfl_xor(mx, off));
            float e[4];
            #pragma unroll
            for (int j = 0; j < 4; ++j) e[j] = __expf(z[j] - mx);
            float ss = (e[0] + e[1]) + (e[2] + e[3]);
            #pragma unroll
            for (int off = 16; off >= 1; off >>= 1) ss += __shfl_xor(ss, off);
            const float inv = 1.0f / ss;
            #pragma unroll
            for (int j = 0; j < 4; ++j) {
                const float t = e[j] * inv;
                out_tf[(size_t)g * M_ + c + 32 * j] = t;
                out_l[p * OPAD_ + c + 32 * j] = t * mv;
            }
        }
    }
    __syncthreads();   // barrier 4: tf*mass tile complete

    // ---------------- Phase 3c: transposed float4 writes of trial_in_t ----------------
    {
        const int mr = tid >> 3;          // 0..31: mode row within slab
        const int pg = tid & 7;           // point group: 4 consecutive points
        #pragma unroll
        for (int it = 0; it < 4; ++it) {
            const int m = it * 32 + mr;
            float4 v;
            v.x = out_l[(pg * 4 + 0) * OPAD_ + m];
            v.y = out_l[(pg * 4 + 1) * OPAD_ + m];
            v.z = out_l[(pg * 4 + 2) * OPAD_ + m];
            v.w = out_l[(pg * 4 + 3) * OPAD_ + m];
            *reinterpret_cast<float4*>(
                out_tit + (size_t)b_idx * M_ * NPTS_ + (size_t)m * NPTS_ + n0 + pg * 4) = v;
        }
    }

    // ---------------- Phase 3d: per-block column sums -> workspace partials ----------------
    if (tid < M_) {
        float s = 0.0f;
        #pragma unroll
        for (int p = 0; p < P_; ++p) s += out_l[p * OPAD_ + tid];
        part[((size_t)(b_idx * M_ + tid)) * BLKS_PER_B + (blockIdx.x & (BLKS_PER_B - 1))] = s;
    }
}

// Reduce partials: one block per (b,m); 2048 partials each.
__global__ __launch_bounds__(256) void finish_kernel(
    const float* __restrict__ part, float* __restrict__ out_inv)
{
    __shared__ float wsum[4];
    const int j = blockIdx.x;           // b*128 + m
    const int t = threadIdx.x;
    const float* row = part + (size_t)j * BLKS_PER_B;
    float s = 0.0f;
    #pragma unroll
    for (int i = 0; i < 8; ++i) s += row[i * 256 + t];
    #pragma unroll
    for (int off = 32; off >= 1; off >>= 1) s += __shfl_xor(s, off);
    if ((t & 63) == 0) wsum[t >> 6] = s;
    __syncthreads();
    if (t == 0) out_inv[j] = 1.0f / (wsum[0] + wsum[1] + wsum[2] + wsum[3] + 1e-6f);
}

extern "C" void kernel_launch(void* const* d_in, const int* in_sizes, int n_in,
                              void* d_out, int out_size, void* d_ws, size_t ws_size,
                              hipStream_t stream) {
    const float* x     = (const float*)d_in[0];
    const float* mass  = (const float*)d_in[1];
    const float* ln_g  = (const float*)d_in[2];
    const float* ln_b  = (const float*)d_in[3];
    const float* W_lin = (const float*)d_in[4];
    const float* b_lin = (const float*)d_in[5];
    const float* W_t1  = (const float*)d_in[6];
    const float* W_t2  = (const float*)d_in[7];
    const float* b_t2  = (const float*)d_in[8];

    __hip_bfloat16* wcat = (__hip_bfloat16*)d_ws;                    // 163,840 B
    float* part          = (float*)((char*)d_ws + NT_ * D_ * 2);     // 2*128*2048 floats = 2 MB

    float* out_tf  = (float*)d_out;                                  // (B,N,M)
    float* out_tit = out_tf + (size_t)2 * NPTS_ * M_;                // (B,M,N)
    float* out_inv = out_tit + (size_t)2 * NPTS_ * M_;               // (B,M,1)

    prep_kernel<<<(NT_ * D_ + 255) / 256, 256, 0, stream>>>(W_lin, W_t1, wcat);

    const int nblocks = (2 * NPTS_) / P_;   // 4096
    main_kernel<<<nblocks, 256, 0, stream>>>(x, mass, ln_g, ln_b, b_lin, W_t2, b_t2,
                                             wcat, out_tf, out_tit, part);

    finish_kernel<<<2 * M_, 256, 0, stream>>>(part, out_inv);
}